// Round 6
// baseline (1158.597 us; speedup 1.0000x reference)
//
#include <hip/hip_runtime.h>
#include <stdint.h>
#include <math.h>

// Problem constants
#define D_MODEL 768
#define NTOK    4096      // B*S = 2*2048
#define SEQ     2048
#define NHEAD   12
#define HDIM    64
#define D_FF    3072
#define QKV_N   2304      // 3*D_MODEL

typedef unsigned short ushort_t;  // raw bf16 bits
typedef short  short8 __attribute__((ext_vector_type(8)));
typedef float  f32x4  __attribute__((ext_vector_type(4)));
typedef float  f32x16 __attribute__((ext_vector_type(16)));

__device__ __forceinline__ float b2f(ushort_t u) {
  union { unsigned int u; float f; } v; v.u = ((unsigned int)u) << 16; return v.f;
}
__device__ __forceinline__ ushort_t f2b(float f) {
  union { float f; unsigned int u; } v; v.f = f;
  unsigned int u = v.u;
  return (ushort_t)((u + 0x7fffu + ((u >> 16) & 1u)) >> 16);  // RNE
}
__device__ __forceinline__ unsigned cvtpk_bf16(float lo, float hi) {
  unsigned r;
  asm("v_cvt_pk_bf16_f32 %0, %1, %2" : "=v"(r) : "v"(lo), "v"(hi));
  return r;
}

// ---------------------------------------------------------------- layer transpose+cast
// All 4 weight matrices of one layer, [K,N] fp32 -> [N,K] bf16, one launch.
__global__ __launch_bounds__(256) void transpose_layer(
    const float* __restrict__ qkv_w, const float* __restrict__ out_w,
    const float* __restrict__ fc1_w, const float* __restrict__ fc2_w,
    ushort_t* __restrict__ qkvT, ushort_t* __restrict__ outT,
    ushort_t* __restrict__ f1T, ushort_t* __restrict__ f2T) {
  __shared__ ushort_t tile[32][33];
  int bid = blockIdx.x;
  const float* src; ushort_t* dst; int K, N, tn, tk;
  if (bid < 1728)      { src = qkv_w; dst = qkvT; K = 768;  N = 2304; tn = bid % 72;  tk = bid / 72; }
  else if (bid < 2304) { int b = bid - 1728; src = out_w; dst = outT; K = 768;  N = 768;  tn = b % 24; tk = b / 24; }
  else if (bid < 4608) { int b = bid - 2304; src = fc1_w; dst = f1T;  K = 768;  N = 3072; tn = b % 96; tk = b / 96; }
  else                 { int b = bid - 4608; src = fc2_w; dst = f2T;  K = 3072; N = 768;  tn = b % 24; tk = b / 24; }
  int n0 = tn * 32, k0 = tk * 32;
  int tx = threadIdx.x, ty = threadIdx.y;       // (32,8)
  #pragma unroll
  for (int i = 0; i < 32; i += 8)
    tile[ty + i][tx] = f2b(src[(size_t)(k0 + ty + i) * N + n0 + tx]);
  __syncthreads();
  #pragma unroll
  for (int i = 0; i < 32; i += 8)
    dst[(size_t)(n0 + ty + i) * K + k0 + tx] = tile[tx][ty + i];
}

// ---------------------------------------------------------------- layernorm
__global__ __launch_bounds__(256) void ln_kernel(const float* __restrict__ x,
                                                 const float* __restrict__ w,
                                                 const float* __restrict__ b,
                                                 ushort_t* __restrict__ out) {
  __shared__ float red[4];
  int tok = blockIdx.x, t = threadIdx.x;
  const float* xr = x + (size_t)tok * D_MODEL;
  float v0 = xr[t], v1 = xr[t + 256], v2 = xr[t + 512];
  float s = v0 + v1 + v2;
  #pragma unroll
  for (int o = 1; o < 64; o <<= 1) s += __shfl_xor(s, o, 64);
  if ((t & 63) == 0) red[t >> 6] = s;
  __syncthreads();
  float mean = (red[0] + red[1] + red[2] + red[3]) * (1.0f / 768.0f);
  __syncthreads();
  float d0 = v0 - mean, d1 = v1 - mean, d2 = v2 - mean;
  float q = d0 * d0 + d1 * d1 + d2 * d2;
  #pragma unroll
  for (int o = 1; o < 64; o <<= 1) q += __shfl_xor(q, o, 64);
  if ((t & 63) == 0) red[t >> 6] = q;
  __syncthreads();
  float var = (red[0] + red[1] + red[2] + red[3]) * (1.0f / 768.0f);
  float rs = rsqrtf(var + 1e-5f);
  ushort_t* orow = out + (size_t)tok * D_MODEL;
  orow[t]       = f2b(d0 * rs * w[t]       + b[t]);
  orow[t + 256] = f2b(d1 * rs * w[t + 256] + b[t + 256]);
  orow[t + 512] = f2b(d2 * rs * w[t + 512] + b[t + 512]);
}

// ---------------------------------------------------------------- GEMM (MFMA bf16)
// C[M,N] = A[M,K] * BT[N,K]^T + bias, 128 x TN tile, BK=32, 256 threads.
// DOUBLE-BUFFERED K-loop: one barrier/iter. XCD-chunked block swizzle (kept:
// non-attn time improved with it).
// EPI: 0 bias->bf16 | 1 bias+gelu->bf16 | 2 bias+resid->fp32
template <int EPI, int TN>
__global__ __launch_bounds__(256) void gemm_kernel(
    const ushort_t* __restrict__ A, const ushort_t* __restrict__ BT,
    const float* __restrict__ bias, const float* __restrict__ resid,
    float* __restrict__ Cf, ushort_t* __restrict__ Cb, int M, int N, int K) {
  constexpr int NI = (TN == 128) ? 4 : 2;
  __shared__ ushort_t As[2][128 * 32];
  __shared__ ushort_t Bs[2][TN * 32];
  int t = threadIdx.x;
  int lane = t & 63, wave = t >> 6;
  // XCD-aware bijective chunk swizzle (T1)
  int gx = gridDim.x;
  int nwg = gx * gridDim.y;
  int bid0 = blockIdx.y * gx + blockIdx.x;
  int qn = nwg >> 3, rm = nwg & 7;
  int xcd = bid0 & 7, pos = bid0 >> 3;
  int wg = (xcd < rm ? xcd * (qn + 1) : rm * (qn + 1) + (xcd - rm) * qn) + pos;
  int m0 = (wg / gx) * 128, n0 = (wg % gx) * TN;
  int wm = (TN == 128) ? (wave & 1) * 64 : wave * 32;
  int wn = (TN == 128) ? (wave >> 1) * 64 : 0;
  int quad = lane >> 4, l16 = lane & 15;
  int kq = quad * 8;
  int lrow = lane >> 2, lcol = (lane & 3) * 8;   // staging: 16B per lane

  auto stage = [&](int k0, int buf) {
    #pragma unroll
    for (int c = 0; c < 2; ++c) {
      int rowA = wave * 32 + c * 16 + lrow;
      const ushort_t* ga = A + (size_t)(m0 + rowA) * K + k0 + lcol;
      ushort_t* la = &As[buf][(wave * 32 + c * 16) * 32];
      __builtin_amdgcn_global_load_lds((const __attribute__((address_space(1))) void*)ga,
                                       (__attribute__((address_space(3))) void*)la, 16, 0, 0);
      if (TN == 128 || c == 0) {
        int rowB = (TN == 128) ? rowA : (wave * 16 + lrow);
        const ushort_t* gb = BT + (size_t)(n0 + rowB) * K + k0 + lcol;
        ushort_t* lb = (TN == 128) ? &Bs[buf][(wave * 32 + c * 16) * 32]
                                   : &Bs[buf][(wave * 16) * 32];
        __builtin_amdgcn_global_load_lds((const __attribute__((address_space(1))) void*)gb,
                                         (__attribute__((address_space(3))) void*)lb, 16, 0, 0);
      }
    }
  };

  f32x4 acc[NI][4];
  #pragma unroll
  for (int i = 0; i < NI; ++i)
    #pragma unroll
    for (int j = 0; j < 4; ++j) acc[i][j] = (f32x4){0.f, 0.f, 0.f, 0.f};

  stage(0, 0);                      // prologue prefetch
  int nk = K / 32;
  for (int ki = 0; ki < nk; ++ki) {
    int cur = ki & 1;
    __syncthreads();                // tile ki resident; prev reads of buf[cur^1] done
    if (ki + 1 < nk) stage((ki + 1) * 32, cur ^ 1);
    short8 af[NI], bf[4];
    #pragma unroll
    for (int i = 0; i < NI; ++i)
      af[i] = *(const short8*)&As[cur][(wm + i * 16 + l16) * 32 + kq];
    #pragma unroll
    for (int j = 0; j < 4; ++j)
      bf[j] = *(const short8*)&Bs[cur][(wn + j * 16 + l16) * 32 + kq];
    #pragma unroll
    for (int i = 0; i < NI; ++i)
      #pragma unroll
      for (int j = 0; j < 4; ++j)
        acc[i][j] = __builtin_amdgcn_mfma_f32_16x16x32_bf16(af[i], bf[j], acc[i][j], 0, 0, 0);
  }

  #pragma unroll
  for (int i = 0; i < NI; ++i) {
    #pragma unroll
    for (int j = 0; j < 4; ++j) {
      int col = n0 + wn + j * 16 + l16;
      float bv = bias[col];
      #pragma unroll
      for (int r = 0; r < 4; ++r) {
        int row = m0 + wm + i * 16 + quad * 4 + r;
        float v = acc[i][j][r] + bv;
        if (EPI == 1) v = 0.5f * v * (1.0f + erff(v * 0.70710678118654752f));
        if (EPI == 2) v += resid[(size_t)row * N + col];
        if (EPI == 2) Cf[(size_t)row * N + col] = v;
        else          Cb[(size_t)row * N + col] = f2b(v);
      }
    }
  }
}

// ---------------------------------------------------------------- attention (r14)
// qkv bf16 [NTOK, 2304]; token t, head hd: [hd*192 + (q:0|k:64|v:128) + d]
// Structure: q-tile 64 (grid 32x24=768, 3 blocks/CU), 4 waves, 4-WAY KEY SPLIT:
// wave w owns keys [32w,+32) of each 128-key superstep x ALL 64 q (qf both
// halves in regs). Zero K/V read redundancy across waves (r4 had 2x on both).
//  - K: per-wave global/L2 -> regs; loads issued at iter top, consumed by QK
//    AFTER the previous superstep's PV (~400cyc of LDS+MFMA+barrier) -> the
//    L2 latency that killed r5 is structurally hidden.
//  - V: LDS double-buffer [2][d64][key 136], b16 transpose writes (conflict-
//    free: consecutive lanes -> consecutive key columns). 34.8KB LDS.
//  - One barrier per superstep: write(buf) | PV(buf^1) race-free since
//    v_write(it+1) (same buf as PV(it-1)) is after barrier(it).
//  - Fixed-max softmax -> key-partials additive; 2-phase tree combine at end.
//  - permlane32_swap P-exchange (algebraically == r4's verified shfl map).
#define KP 136
__global__ __launch_bounds__(256, 3) void attn_kernel(const ushort_t* __restrict__ qkv,
                                                      ushort_t* __restrict__ out) {
  __shared__ __align__(16) ushort_t Vt[2][64 * KP];   // [buf][d][key] 2x17408B
  int t = threadIdx.x;
  int lane = t & 63, wave = t >> 6;
  int l31 = lane & 31, h = lane >> 5, h8 = h * 8;
  int kw = wave * 32;                 // wave's key window within 128-key superstep
  int qt = blockIdx.x;                // 64-row q tile
  int bh = blockIdx.y;
  int b = bh / NHEAD, hd = bh % NHEAD;
  size_t base = (size_t)b * SEQ * QKV_N + hd * 192;
  const float kscale = 0.125f * 1.44269504088896f;  // scale * log2(e)

  // Q fragments, both q-halves: B-operand col = q = 32qh + l31, elem e <-> d = 16ks+8h+e
  short8 qf[2][4];
  #pragma unroll
  for (int qh = 0; qh < 2; ++qh) {
    const ushort_t* qp = qkv + base + (size_t)(qt * 64 + qh * 32 + l31) * QKV_N + h8;
    #pragma unroll
    for (int ks = 0; ks < 4; ++ks) qf[qh][ks] = *(const short8*)(qp + ks * 16);
  }

  // V staging: thread -> key vk = t&127, d-half vdb = (t>>7)*32 (32 elems)
  int vk = t & 127, vdb = (t >> 7) * 32;
  short8 va[4];
  auto v_load = [&](int sb) {
    const ushort_t* gv = qkv + base + (size_t)(sb + vk) * QKV_N + 128 + vdb;
    #pragma unroll
    for (int i = 0; i < 4; ++i) va[i] = *(const short8*)(gv + i * 8);
  };
  auto v_write = [&](int buf) {
    #pragma unroll
    for (int i = 0; i < 4; ++i)
      #pragma unroll
      for (int e = 0; e < 8; ++e)
        Vt[buf][(vdb + i * 8 + e) * KP + vk] = (ushort_t)va[i][e];
  };

  f32x16 o[2][2];                // [qh][dh]: q = 32qh + (8g+4h+r), d = 32dh + l31
  #pragma unroll
  for (int qh = 0; qh < 2; ++qh)
    #pragma unroll
    for (int dh = 0; dh < 2; ++dh)
      #pragma unroll
      for (int i = 0; i < 16; ++i) o[qh][dh][i] = 0.f;
  float ls[2] = {0.f, 0.f};      // partial denominators (q = 32qh + l31, own-h rows)
  unsigned wq[2][4][2];          // packed P for the pending superstep

  auto PV = [&](int buf) {
    #pragma unroll
    for (int k4 = 0; k4 < 2; ++k4) {
      short8 v0 = *(const short8*)&Vt[buf][(size_t)(l31)      * KP + kw + k4 * 16 + h8];
      short8 v1 = *(const short8*)&Vt[buf][(size_t)(32 + l31) * KP + kw + k4 * 16 + h8];
      #pragma unroll
      for (int qh = 0; qh < 2; ++qh) {
        int j2 = k4 * 2;
        unsigned f0, f1, f2, f3;
        { unsigned x = wq[qh][j2][0], y = wq[qh][j2 + 1][0];
          asm("v_permlane32_swap_b32 %0, %1" : "+v"(y), "+v"(x));
          f0 = x; f2 = y; }
        { unsigned x = wq[qh][j2][1], y = wq[qh][j2 + 1][1];
          asm("v_permlane32_swap_b32 %0, %1" : "+v"(y), "+v"(x));
          f1 = x; f3 = y; }
        union { unsigned u[4]; short8 s8; } uc;
        uc.u[0] = f0; uc.u[1] = f1; uc.u[2] = f2; uc.u[3] = f3;
        __builtin_amdgcn_s_setprio(1);
        o[qh][0] = __builtin_amdgcn_mfma_f32_32x32x16_bf16(uc.s8, v0, o[qh][0], 0, 0, 0);
        o[qh][1] = __builtin_amdgcn_mfma_f32_32x32x16_bf16(uc.s8, v1, o[qh][1], 0, 0, 0);
        __builtin_amdgcn_s_setprio(0);
      }
    }
  };

  v_load(0);
  const int NSS = SEQ / 128;
  for (int it = 0; it < NSS; ++it) {
    int buf = it & 1;
    v_write(buf);                          // concurrent-safe: PV below reads buf^1
    if (it + 1 < NSS) v_load((it + 1) * 128);
    // K fragments for THIS superstep: issue now, consumed after PV+barrier
    short8 kf[4];
    {
      const ushort_t* gk = qkv + base + (size_t)(it * 128 + kw + l31) * QKV_N + 64 + h8;
      #pragma unroll
      for (int ks = 0; ks < 4; ++ks) kf[ks] = *(const short8*)(gk + ks * 16);
    }
    if (it > 0) PV(buf ^ 1);               // previous superstep's PV (hides kf latency)
    __syncthreads();                       // buf staged for all; prev buf free for it+1

    // ---- QK^T (swapped) + softmax numerator per q-half
    #pragma unroll
    for (int qh = 0; qh < 2; ++qh) {
      f32x16 s;
      #pragma unroll
      for (int i = 0; i < 16; ++i) s[i] = 0.f;
      __builtin_amdgcn_s_setprio(1);
      #pragma unroll
      for (int ks = 0; ks < 4; ++ks)
        s = __builtin_amdgcn_mfma_f32_32x32x16_bf16(kf[ks], qf[qh][ks], s, 0, 0, 0);
      __builtin_amdgcn_s_setprio(0);
      #pragma unroll
      for (int g = 0; g < 4; ++g) {
        float p0 = exp2f(s[4 * g + 0] * kscale), p1 = exp2f(s[4 * g + 1] * kscale);
        float p2 = exp2f(s[4 * g + 2] * kscale), p3 = exp2f(s[4 * g + 3] * kscale);
        ls[qh] += (p0 + p1) + (p2 + p3);
        wq[qh][g][0] = cvtpk_bf16(p0, p1);
        wq[qh][g][1] = cvtpk_bf16(p2, p3);
      }
    }
  }
  PV((NSS - 1) & 1);                       // drain the pipeline
  __syncthreads();                         // all Vt reads done before slab overwrite

  // ---- combine across 4 key-split waves (partials additive)
  float* slab = (float*)&Vt[0][0];
  if (wave >= 2) {
    float* sp = slab + (size_t)((wave - 2) * 64 + lane) * 66;
    #pragma unroll
    for (int qh = 0; qh < 2; ++qh)
      #pragma unroll
      for (int dh = 0; dh < 2; ++dh)
        #pragma unroll
        for (int i = 0; i < 16; ++i) sp[(qh * 2 + dh) * 16 + i] = o[qh][dh][i];
    sp[64] = ls[0]; sp[65] = ls[1];
  }
  __syncthreads();
  if (wave < 2) {
    float* sp = slab + (size_t)(wave * 64 + lane) * 66;
    #pragma unroll
    for (int qh = 0; qh < 2; ++qh)
      #pragma unroll
      for (int dh = 0; dh < 2; ++dh)
        #pragma unroll
        for (int i = 0; i < 16; ++i) o[qh][dh][i] += sp[(qh * 2 + dh) * 16 + i];
    ls[0] += sp[64]; ls[1] += sp[65];
  }
  __syncthreads();
  // phase 2: swap q-halves so wave0 owns full qh0, wave1 full qh1
  if (wave == 0) {
    float* sp = slab + (size_t)lane * 34;
    #pragma unroll
    for (int dh = 0; dh < 2; ++dh)
      #pragma unroll
      for (int i = 0; i < 16; ++i) sp[dh * 16 + i] = o[1][dh][i];
    sp[32] = ls[1];
  } else if (wave == 1) {
    float* sp = slab + (size_t)(64 + lane) * 34;
    #pragma unroll
    for (int dh = 0; dh < 2; ++dh)
      #pragma unroll
      for (int i = 0; i < 16; ++i) sp[dh * 16 + i] = o[0][dh][i];
    sp[32] = ls[0];
  }
  __syncthreads();
  if (wave < 2) {
    float* sp = slab + (size_t)(wave == 0 ? (64 + lane) : lane) * 34;
    f32x16 pa, pb; float lf;
    if (wave == 0) { pa = o[0][0]; pb = o[0][1]; lf = ls[0]; }
    else           { pa = o[1][0]; pb = o[1][1]; lf = ls[1]; }
    #pragma unroll
    for (int i = 0; i < 16; ++i) { pa[i] += sp[i]; pb[i] += sp[16 + i]; }
    lf += sp[32];
    lf += __shfl_xor(lf, 32, 64);          // fold h-partner key rows

    size_t ob = (size_t)(b * SEQ + qt * 64 + wave * 32) * D_MODEL + hd * HDIM;
    #pragma unroll
    for (int g = 0; g < 4; ++g) {
      #pragma unroll
      for (int r = 0; r < 4; ++r) {
        int reg = 4 * g + r;
        int qrow = 8 * g + 4 * h + r;
        float inv = 1.0f / __shfl(lf, qrow, 64);
        ushort_t* orow = out + ob + (size_t)qrow * D_MODEL;
        orow[l31]      = f2b(pa[reg] * inv);
        orow[32 + l31] = f2b(pb[reg] * inv);
      }
    }
  }
}

// ---------------------------------------------------------------- launch
extern "C" void kernel_launch(void* const* d_in, const int* in_sizes, int n_in,
                              void* d_out, int out_size, void* d_ws, size_t ws_size,
                              hipStream_t stream) {
  const float* x_in  = (const float*)d_in[0];
  const float* qkv_w = (const float*)d_in[1];
  const float* qkv_b = (const float*)d_in[2];
  const float* out_w = (const float*)d_in[3];
  const float* out_b = (const float*)d_in[4];
  const float* ln1_w = (const float*)d_in[5];
  const float* ln1_b = (const float*)d_in[6];
  const float* fc1_w = (const float*)d_in[7];
  const float* fc1_b = (const float*)d_in[8];
  const float* fc2_w = (const float*)d_in[9];
  const float* fc2_b = (const float*)d_in[10];
  const float* ln2_w = (const float*)d_in[11];
  const float* ln2_b = (const float*)d_in[12];

  char* ws = (char*)d_ws;
  size_t off = 0;
  auto alloc = [&](size_t bytes) -> void* {
    void* p = ws + off; off += (bytes + 255) & ~(size_t)255; return p;
  };
  float*    buf_x  = (float*)   alloc((size_t)NTOK * D_MODEL * 4);
  float*    buf_x2 = (float*)   alloc((size_t)NTOK * D_MODEL * 4);
  ushort_t* bigb   = (ushort_t*)alloc((size_t)NTOK * D_FF * 2);     // qkv_a / mlp_b union
  ushort_t* h_b    = (ushort_t*)alloc((size_t)NTOK * D_MODEL * 2);
  ushort_t* at_b   = (ushort_t*)alloc((size_t)NTOK * D_MODEL * 2);
  ushort_t* qkvT   = (ushort_t*)alloc((size_t)QKV_N * D_MODEL * 2);
  ushort_t* outT   = (ushort_t*)alloc((size_t)D_MODEL * D_MODEL * 2);
  ushort_t* f1T    = (ushort_t*)alloc((size_t)D_FF * D_MODEL * 2);
  ushort_t* f2T    = (ushort_t*)alloc((size_t)D_MODEL * D_FF * 2);

  ushort_t* qkv_a = bigb;
  ushort_t* mlp_b = bigb;

  for (int l = 0; l < 4; ++l) {
    const float* resid_in = (l == 0) ? x_in : buf_x;
    transpose_layer<<<6912, dim3(32, 8), 0, stream>>>(
        qkv_w + (size_t)l * D_MODEL * QKV_N, out_w + (size_t)l * D_MODEL * D_MODEL,
        fc1_w + (size_t)l * D_MODEL * D_FF,  fc2_w + (size_t)l * D_FF * D_MODEL,
        qkvT, outT, f1T, f2T);
    ln_kernel<<<NTOK, 256, 0, stream>>>(resid_in, ln1_w + l * D_MODEL, ln1_b + l * D_MODEL, h_b);
    gemm_kernel<0, 128><<<dim3(QKV_N / 128, NTOK / 128), 256, 0, stream>>>(
        h_b, qkvT, qkv_b + l * QKV_N, nullptr, nullptr, qkv_a, NTOK, QKV_N, D_MODEL);
    attn_kernel<<<dim3(SEQ / 64, 2 * NHEAD), 256, 0, stream>>>(qkv_a, at_b);
    gemm_kernel<2, 64><<<dim3(D_MODEL / 64, NTOK / 128), 256, 0, stream>>>(
        at_b, outT, out_b + l * D_MODEL, resid_in, buf_x2, nullptr, NTOK, D_MODEL, D_MODEL);
    ln_kernel<<<NTOK, 256, 0, stream>>>(buf_x2, ln2_w + l * D_MODEL, ln2_b + l * D_MODEL, h_b);
    gemm_kernel<1, 128><<<dim3(D_FF / 128, NTOK / 128), 256, 0, stream>>>(
        h_b, f1T, fc1_b + l * D_FF, nullptr, nullptr, mlp_b, NTOK, D_FF, D_MODEL);
    float* x_next = (l < 3) ? buf_x : (float*)d_out;
    gemm_kernel<2, 64><<<dim3(D_MODEL / 64, NTOK / 128), 256, 0, stream>>>(
        mlp_b, f2T, fc2_b + l * D_MODEL, buf_x2, x_next, nullptr, NTOK, D_MODEL, D_FF);
  }
  (void)in_sizes; (void)n_in; (void)out_size; (void)ws_size;
}

// Round 7
// 943.571 us; speedup vs baseline: 1.2279x; 1.2279x over previous
//
#include <hip/hip_runtime.h>
#include <stdint.h>
#include <math.h>

// Problem constants
#define D_MODEL 768
#define NTOK    4096      // B*S = 2*2048
#define SEQ     2048
#define NHEAD   12
#define HDIM    64
#define D_FF    3072
#define QKV_N   2304      // 3*D_MODEL

typedef unsigned short ushort_t;  // raw bf16 bits
typedef short  short8 __attribute__((ext_vector_type(8)));
typedef float  f32x4  __attribute__((ext_vector_type(4)));
typedef float  f32x16 __attribute__((ext_vector_type(16)));

__device__ __forceinline__ float b2f(ushort_t u) {
  union { unsigned int u; float f; } v; v.u = ((unsigned int)u) << 16; return v.f;
}
__device__ __forceinline__ ushort_t f2b(float f) {
  union { float f; unsigned int u; } v; v.f = f;
  unsigned int u = v.u;
  return (ushort_t)((u + 0x7fffu + ((u >> 16) & 1u)) >> 16);  // RNE
}
__device__ __forceinline__ unsigned cvtpk_bf16(float lo, float hi) {
  unsigned r;
  asm("v_cvt_pk_bf16_f32 %0, %1, %2" : "=v"(r) : "v"(lo), "v"(hi));
  return r;
}

// ---------------------------------------------------------------- weight transpose+cast
// [K,N] fp32 -> [N,K] bf16. blockIdx.y = layer (grid.y=4 all-layer mode, 1 per-layer).
__global__ __launch_bounds__(256) void transpose_layers(
    const float* __restrict__ qkv_w, const float* __restrict__ out_w,
    const float* __restrict__ fc1_w, const float* __restrict__ fc2_w,
    ushort_t* __restrict__ qkvT, ushort_t* __restrict__ outT,
    ushort_t* __restrict__ f1T, ushort_t* __restrict__ f2T) {
  __shared__ ushort_t tile[32][33];
  int bid = blockIdx.x;
  size_t l = blockIdx.y;
  const float* src; ushort_t* dst; int K, N, tn, tk;
  if (bid < 1728)      { src = qkv_w + l * D_MODEL * QKV_N; dst = qkvT + l * D_MODEL * QKV_N;
                         K = 768;  N = 2304; tn = bid % 72;  tk = bid / 72; }
  else if (bid < 2304) { int b = bid - 1728; src = out_w + l * D_MODEL * D_MODEL; dst = outT + l * D_MODEL * D_MODEL;
                         K = 768;  N = 768;  tn = b % 24; tk = b / 24; }
  else if (bid < 4608) { int b = bid - 2304; src = fc1_w + l * D_MODEL * D_FF; dst = f1T + l * D_MODEL * D_FF;
                         K = 768;  N = 3072; tn = b % 96; tk = b / 96; }
  else                 { int b = bid - 4608; src = fc2_w + l * D_FF * D_MODEL; dst = f2T + l * D_FF * D_MODEL;
                         K = 3072; N = 768;  tn = b % 24; tk = b / 24; }
  int n0 = tn * 32, k0 = tk * 32;
  int tx = threadIdx.x, ty = threadIdx.y;       // (32,8)
  #pragma unroll
  for (int i = 0; i < 32; i += 8)
    tile[ty + i][tx] = f2b(src[(size_t)(k0 + ty + i) * N + n0 + tx]);
  __syncthreads();
  #pragma unroll
  for (int i = 0; i < 32; i += 8)
    dst[(size_t)(n0 + ty + i) * K + k0 + tx] = tile[tx][ty + i];
}

// ---------------------------------------------------------------- layernorm
__global__ __launch_bounds__(256) void ln_kernel(const float* __restrict__ x,
                                                 const float* __restrict__ w,
                                                 const float* __restrict__ b,
                                                 ushort_t* __restrict__ out) {
  __shared__ float red[4];
  int tok = blockIdx.x, t = threadIdx.x;
  const float* xr = x + (size_t)tok * D_MODEL;
  float v0 = xr[t], v1 = xr[t + 256], v2 = xr[t + 512];
  float s = v0 + v1 + v2;
  #pragma unroll
  for (int o = 1; o < 64; o <<= 1) s += __shfl_xor(s, o, 64);
  if ((t & 63) == 0) red[t >> 6] = s;
  __syncthreads();
  float mean = (red[0] + red[1] + red[2] + red[3]) * (1.0f / 768.0f);
  __syncthreads();
  float d0 = v0 - mean, d1 = v1 - mean, d2 = v2 - mean;
  float q = d0 * d0 + d1 * d1 + d2 * d2;
  #pragma unroll
  for (int o = 1; o < 64; o <<= 1) q += __shfl_xor(q, o, 64);
  if ((t & 63) == 0) red[t >> 6] = q;
  __syncthreads();
  float var = (red[0] + red[1] + red[2] + red[3]) * (1.0f / 768.0f);
  float rs = rsqrtf(var + 1e-5f);
  ushort_t* orow = out + (size_t)tok * D_MODEL;
  orow[t]       = f2b(d0 * rs * w[t]       + b[t]);
  orow[t + 256] = f2b(d1 * rs * w[t + 256] + b[t + 256]);
  orow[t + 512] = f2b(d2 * rs * w[t + 512] + b[t + 512]);
}

// ---------------------------------------------------------------- GEMM (MFMA bf16)
// C[M,N] = A[M,K] * BT[N,K]^T + bias, 128 x TN tile, BK=32, 256 threads.
// DOUBLE-BUFFERED K-loop: one barrier/iter. XCD-chunked block swizzle.
// EPI: 0 bias->bf16 | 1 bias+gelu(tanh approx, max err ~1e-3 << bf16 eps)->bf16
//      2 bias+resid->fp32
template <int EPI, int TN>
__global__ __launch_bounds__(256) void gemm_kernel(
    const ushort_t* __restrict__ A, const ushort_t* __restrict__ BT,
    const float* __restrict__ bias, const float* __restrict__ resid,
    float* __restrict__ Cf, ushort_t* __restrict__ Cb, int M, int N, int K) {
  constexpr int NI = (TN == 128) ? 4 : 2;
  __shared__ ushort_t As[2][128 * 32];
  __shared__ ushort_t Bs[2][TN * 32];
  int t = threadIdx.x;
  int lane = t & 63, wave = t >> 6;
  // XCD-aware bijective chunk swizzle (T1)
  int gx = gridDim.x;
  int nwg = gx * gridDim.y;
  int bid0 = blockIdx.y * gx + blockIdx.x;
  int qn = nwg >> 3, rm = nwg & 7;
  int xcd = bid0 & 7, pos = bid0 >> 3;
  int wg = (xcd < rm ? xcd * (qn + 1) : rm * (qn + 1) + (xcd - rm) * qn) + pos;
  int m0 = (wg / gx) * 128, n0 = (wg % gx) * TN;
  int wm = (TN == 128) ? (wave & 1) * 64 : wave * 32;
  int wn = (TN == 128) ? (wave >> 1) * 64 : 0;
  int quad = lane >> 4, l16 = lane & 15;
  int kq = quad * 8;
  int lrow = lane >> 2, lcol = (lane & 3) * 8;   // staging: 16B per lane

  auto stage = [&](int k0, int buf) {
    #pragma unroll
    for (int c = 0; c < 2; ++c) {
      int rowA = wave * 32 + c * 16 + lrow;
      const ushort_t* ga = A + (size_t)(m0 + rowA) * K + k0 + lcol;
      ushort_t* la = &As[buf][(wave * 32 + c * 16) * 32];
      __builtin_amdgcn_global_load_lds((const __attribute__((address_space(1))) void*)ga,
                                       (__attribute__((address_space(3))) void*)la, 16, 0, 0);
      if (TN == 128 || c == 0) {
        int rowB = (TN == 128) ? rowA : (wave * 16 + lrow);
        const ushort_t* gb = BT + (size_t)(n0 + rowB) * K + k0 + lcol;
        ushort_t* lb = (TN == 128) ? &Bs[buf][(wave * 32 + c * 16) * 32]
                                   : &Bs[buf][(wave * 16) * 32];
        __builtin_amdgcn_global_load_lds((const __attribute__((address_space(1))) void*)gb,
                                         (__attribute__((address_space(3))) void*)lb, 16, 0, 0);
      }
    }
  };

  f32x4 acc[NI][4];
  #pragma unroll
  for (int i = 0; i < NI; ++i)
    #pragma unroll
    for (int j = 0; j < 4; ++j) acc[i][j] = (f32x4){0.f, 0.f, 0.f, 0.f};

  stage(0, 0);                      // prologue prefetch
  int nk = K / 32;
  for (int ki = 0; ki < nk; ++ki) {
    int cur = ki & 1;
    __syncthreads();                // tile ki resident; prev reads of buf[cur^1] done
    if (ki + 1 < nk) stage((ki + 1) * 32, cur ^ 1);
    short8 af[NI], bf[4];
    #pragma unroll
    for (int i = 0; i < NI; ++i)
      af[i] = *(const short8*)&As[cur][(wm + i * 16 + l16) * 32 + kq];
    #pragma unroll
    for (int j = 0; j < 4; ++j)
      bf[j] = *(const short8*)&Bs[cur][(wn + j * 16 + l16) * 32 + kq];
    #pragma unroll
    for (int i = 0; i < NI; ++i)
      #pragma unroll
      for (int j = 0; j < 4; ++j)
        acc[i][j] = __builtin_amdgcn_mfma_f32_16x16x32_bf16(af[i], bf[j], acc[i][j], 0, 0, 0);
  }

  #pragma unroll
  for (int i = 0; i < NI; ++i) {
    #pragma unroll
    for (int j = 0; j < 4; ++j) {
      int col = n0 + wn + j * 16 + l16;
      float bv = bias[col];
      #pragma unroll
      for (int r = 0; r < 4; ++r) {
        int row = m0 + wm + i * 16 + quad * 4 + r;
        float v = acc[i][j][r] + bv;
        if (EPI == 1) {
          // gelu tanh-form: v * e/(e+1), e = exp2(2.302208*(v + 0.044715 v^3))
          float u = v + 0.044715f * v * v * v;
          u = fminf(u, 30.0f);                    // avoid inf/inf
          float e = exp2f(2.302207848f * u);
          v = v * e / (e + 1.0f);
        }
        if (EPI == 2) v += resid[(size_t)row * N + col];
        if (EPI == 2) Cf[(size_t)row * N + col] = v;
        else          Cb[(size_t)row * N + col] = f2b(v);
      }
    }
  }
}

// ---------------------------------------------------------------- attention (MFMA 32x32, 2x2 wave partition)
// qkv bf16 [NTOK, 2304]; token t, head hd: [hd*192 + (q:0|k:64|v:128) + d]
// r4-proven structure (62.4us, VGPR 68, zero conflicts, no spill):
// q-tile 64, 256 thr, 3 blocks/CU, 36.8KB LDS, 128-key supersteps staged as
// 2 chunks; waves partition (key-half x q-half): wave (kh=w&1, qh=w>>1)
// processes keys [32kh,+32) of BOTH chunks x q [32qh,+32).
// Fixed-max softmax -> key-partials additive -> one LDS exchange at end.
__global__ __launch_bounds__(256, 3) void attn_kernel(const ushort_t* __restrict__ qkv,
                                                      ushort_t* __restrict__ out) {
  __shared__ __align__(16) ushort_t Ks[2][64 * 72];   // [chunk][key][d], pad 72
  __shared__ __align__(16) ushort_t Vt[2][64 * 72];   // [chunk][d][key], pad 72
  int t = threadIdx.x;
  int lane = t & 63, wave = t >> 6;
  int l31 = lane & 31, h = lane >> 5, h8 = h * 8;
  int kh = wave & 1, qh = wave >> 1;
  int kw = kh * 32;                    // wave's key window within each 64-key chunk
  int qt = blockIdx.x;
  int bh = blockIdx.y;
  int b = bh / NHEAD, hd = bh % NHEAD;
  size_t base = (size_t)b * SEQ * QKV_N + hd * 192;

  const float kscale = 0.125f * 1.44269504088896f;  // scale * log2(e)

  // Q fragments (own q-half): B-operand col = q = qh*32 + l31, elem e <-> d = 16*ks + 8*h + e
  short8 qf[4];
  {
    const ushort_t* qp = qkv + base + (size_t)(qt * 64 + qh * 32 + l31) * QKV_N + h8;
    #pragma unroll
    for (int ks = 0; ks < 4; ++ks) qf[ks] = *(const short8*)(qp + ks * 16);
  }

  // staging (256 threads stage the whole 128-key superstep into 2 chunks):
  // K: thread -> row krow (0..127), 32 d at kcol; 4x b128 writes
  // V: thread -> key-pair (2kp, 2kp+1), 16 d at vdb; packed b32 transposed writes
  int krow = t >> 1, kcol = (t & 1) * 32;
  int kcb = krow >> 6, krl = krow & 63;
  int kp = t & 63, vdb = (t >> 6) * 16;
  int vcb = kp >> 5, kpl = kp & 31;
  short8 kr[4], va[2], vb[2];
  auto kv_load = [&](int sbase) {
    const ushort_t* gk = qkv + base + (size_t)(sbase + krow) * QKV_N + 64 + kcol;
    #pragma unroll
    for (int i = 0; i < 4; ++i) kr[i] = *(const short8*)(gk + i * 8);
    const ushort_t* gv = qkv + base + (size_t)(sbase + 2 * kp) * QKV_N + 128 + vdb;
    va[0] = *(const short8*)gv;           va[1] = *(const short8*)(gv + 8);
    vb[0] = *(const short8*)(gv + QKV_N); vb[1] = *(const short8*)(gv + QKV_N + 8);
  };
  auto kv_write = [&]() {
    #pragma unroll
    for (int i = 0; i < 4; ++i)
      *(short8*)&Ks[kcb][krl * 72 + kcol + i * 8] = kr[i];
    unsigned* vtw = (unsigned*)&Vt[vcb][0];
    #pragma unroll
    for (int half = 0; half < 2; ++half)
      #pragma unroll
      for (int e = 0; e < 8; ++e) {
        unsigned pk = (unsigned)(unsigned short)va[half][e] |
                      ((unsigned)(unsigned short)vb[half][e] << 16);
        vtw[(vdb + half * 8 + e) * 36 + kpl] = pk;   // Vt[d][keys 2kpl, 2kpl+1]
      }
  };

  f32x16 o0, o1;                 // O[q = qh*32 + (8g+4h+r)][d = l31 / 32+l31]
  #pragma unroll
  for (int i = 0; i < 16; ++i) { o0[i] = 0.f; o1[i] = 0.f; }
  float ls = 0.f;                // partial denominator for q = qh*32 + l31

  kv_load(0);
  for (int it = 0; it < SEQ / 128; ++it) {
    kv_write();
    __syncthreads();                       // superstep staged; prev reads done
    if (it + 1 < SEQ / 128) kv_load((it + 1) * 128);

    #pragma unroll
    for (int c = 0; c < 2; ++c) {          // the two 64-key chunks
      // ---- QK^T (swapped): S^T[key, q]; A = K (own 32-key window), B = Q (own q-half)
      f32x16 s;
      #pragma unroll
      for (int i = 0; i < 16; ++i) s[i] = 0.f;
      __builtin_amdgcn_s_setprio(1);
      #pragma unroll
      for (int ks = 0; ks < 4; ++ks) {
        short8 kf = *(const short8*)&Ks[c][(kw + l31) * 72 + ks * 16 + h8];
        s = __builtin_amdgcn_mfma_f32_32x32x16_bf16(kf, qf[ks], s, 0, 0, 0);
      }
      __builtin_amdgcn_s_setprio(0);

      // ---- softmax numerator (fixed max = 0); reg (4g+r) <-> window-key = 8g+4h+r
      unsigned wpk[4][2];
      #pragma unroll
      for (int g = 0; g < 4; ++g) {
        float p0 = exp2f(s[4 * g + 0] * kscale), p1 = exp2f(s[4 * g + 1] * kscale);
        float p2 = exp2f(s[4 * g + 2] * kscale), p3 = exp2f(s[4 * g + 3] * kscale);
        ls += (p0 + p1) + (p2 + p3);
        wpk[g][0] = cvtpk_bf16(p0, p1);
        wpk[g][1] = cvtpk_bf16(p2, p3);
      }

      // ---- PV: O += P * V over own 32-key window; A-frag via half-wave exchange
      #pragma unroll
      for (int k4 = 0; k4 < 2; ++k4) {
        int j2 = k4 * 2;
        unsigned f[4];
        #pragma unroll
        for (int c2 = 0; c2 < 2; ++c2) {
          unsigned a  = wpk[j2][c2];        // window-keys 16k4 + 4h + {2c2, 2c2+1}
          unsigned b2 = wpk[j2 + 1][c2];    // window-keys 16k4 + 8 + 4h + {2c2, 2c2+1}
          unsigned snd = h ? a : b2;
          unsigned rcv = (unsigned)__shfl_xor((int)snd, 32, 64);
          f[c2]     = h ? rcv : a;
          f[2 + c2] = h ? b2 : rcv;
        }
        union { unsigned u[4]; short8 s8; } uc;
        uc.u[0] = f[0]; uc.u[1] = f[1]; uc.u[2] = f[2]; uc.u[3] = f[3];
        short8 ap = uc.s8;
        short8 v0 = *(const short8*)&Vt[c][(l31)      * 72 + kw + k4 * 16 + h8];
        short8 v1 = *(const short8*)&Vt[c][(32 + l31) * 72 + kw + k4 * 16 + h8];
        __builtin_amdgcn_s_setprio(1);
        o0 = __builtin_amdgcn_mfma_f32_32x32x16_bf16(ap, v0, o0, 0, 0, 0);
        o1 = __builtin_amdgcn_mfma_f32_32x32x16_bf16(ap, v1, o1, 0, 0, 0);
        __builtin_amdgcn_s_setprio(0);
      }
    }
    __syncthreads();                       // all reads done before next superstep writes
  }

  // ---- combine key-halves: wave (1,qh) -> wave (0,qh); partials additive
  float* slab = (float*)&Ks[0][0];         // 128 lanes x 33 f = 16896B (fits in Ks)
  if (kh == 1) {
    float* s = slab + (size_t)(qh * 64 + lane) * 33;
    #pragma unroll
    for (int i = 0; i < 16; ++i) { s[i] = o0[i]; s[16 + i] = o1[i]; }
    s[32] = ls;
  }
  __syncthreads();
  if (kh == 0) {
    float* s = slab + (size_t)(qh * 64 + lane) * 33;
    #pragma unroll
    for (int i = 0; i < 16; ++i) { o0[i] += s[i]; o1[i] += s[16 + i]; }
    ls += s[32];
    // fold h-partner (each lane's ls covers only own-h window rows)
    ls += __shfl_xor(ls, 32, 64);

    // epilogue: rows q = qt*64 + qh*32 + (8g+4h+r); cols d = l31 / 32+l31
    size_t ob = (size_t)(b * SEQ + qt * 64 + qh * 32) * D_MODEL + hd * HDIM;
    #pragma unroll
    for (int g = 0; g < 4; ++g) {
      #pragma unroll
      for (int r = 0; r < 4; ++r) {
        int reg = 4 * g + r;
        int qrow = 8 * g + 4 * h + r;
        float inv = 1.0f / __shfl(ls, qrow, 64);
        ushort_t* orow = out + ob + (size_t)qrow * D_MODEL;
        orow[l31]      = f2b(o0[reg] * inv);
        orow[32 + l31] = f2b(o1[reg] * inv);
      }
    }
  }
}

// ---------------------------------------------------------------- launch
extern "C" void kernel_launch(void* const* d_in, const int* in_sizes, int n_in,
                              void* d_out, int out_size, void* d_ws, size_t ws_size,
                              hipStream_t stream) {
  const float* x_in  = (const float*)d_in[0];
  const float* qkv_w = (const float*)d_in[1];
  const float* qkv_b = (const float*)d_in[2];
  const float* out_w = (const float*)d_in[3];
  const float* out_b = (const float*)d_in[4];
  const float* ln1_w = (const float*)d_in[5];
  const float* ln1_b = (const float*)d_in[6];
  const float* fc1_w = (const float*)d_in[7];
  const float* fc1_b = (const float*)d_in[8];
  const float* fc2_w = (const float*)d_in[9];
  const float* fc2_b = (const float*)d_in[10];
  const float* ln2_w = (const float*)d_in[11];
  const float* ln2_b = (const float*)d_in[12];

  char* ws = (char*)d_ws;
  size_t off = 0;
  auto alloc = [&](size_t bytes) -> void* {
    void* p = ws + off; off += (bytes + 255) & ~(size_t)255; return p;
  };
  float*    buf_x  = (float*)   alloc((size_t)NTOK * D_MODEL * 4);
  float*    buf_x2 = (float*)   alloc((size_t)NTOK * D_MODEL * 4);
  ushort_t* bigb   = (ushort_t*)alloc((size_t)NTOK * D_FF * 2);     // qkv_a / mlp_b union
  ushort_t* h_b    = (ushort_t*)alloc((size_t)NTOK * D_MODEL * 2);
  ushort_t* at_b   = (ushort_t*)alloc((size_t)NTOK * D_MODEL * 2);

  // weight transpose buffers: all-layer (1 launch) if ws allows, else per-layer
  size_t per_layer_w = ((size_t)QKV_N * D_MODEL + (size_t)D_MODEL * D_MODEL +
                        (size_t)D_FF * D_MODEL * 2) * 2;            // bytes/layer
  bool all_layers = (ws_size >= off + 4 * per_layer_w + (4 << 10));
  int nl = all_layers ? 4 : 1;
  ushort_t* qkvT = (ushort_t*)alloc((size_t)QKV_N * D_MODEL * 2 * nl);
  ushort_t* outT = (ushort_t*)alloc((size_t)D_MODEL * D_MODEL * 2 * nl);
  ushort_t* f1T  = (ushort_t*)alloc((size_t)D_FF * D_MODEL * 2 * nl);
  ushort_t* f2T  = (ushort_t*)alloc((size_t)D_MODEL * D_FF * 2 * nl);

  ushort_t* qkv_a = bigb;
  ushort_t* mlp_b = bigb;

  if (all_layers)
    transpose_layers<<<dim3(6912, 4), dim3(32, 8), 0, stream>>>(
        qkv_w, out_w, fc1_w, fc2_w, qkvT, outT, f1T, f2T);

  for (int l = 0; l < 4; ++l) {
    const float* resid_in = (l == 0) ? x_in : buf_x;
    size_t lw = all_layers ? (size_t)l : 0;
    ushort_t* qkvT_l = qkvT + lw * QKV_N * D_MODEL;
    ushort_t* outT_l = outT + lw * D_MODEL * D_MODEL;
    ushort_t* f1T_l  = f1T  + lw * D_FF * D_MODEL;
    ushort_t* f2T_l  = f2T  + lw * D_MODEL * D_FF;
    if (!all_layers)
      transpose_layers<<<dim3(6912, 1), dim3(32, 8), 0, stream>>>(
          qkv_w + (size_t)l * D_MODEL * QKV_N, out_w + (size_t)l * D_MODEL * D_MODEL,
          fc1_w + (size_t)l * D_MODEL * D_FF,  fc2_w + (size_t)l * D_FF * D_MODEL,
          qkvT_l, outT_l, f1T_l, f2T_l);
    ln_kernel<<<NTOK, 256, 0, stream>>>(resid_in, ln1_w + l * D_MODEL, ln1_b + l * D_MODEL, h_b);
    gemm_kernel<0, 128><<<dim3(QKV_N / 128, NTOK / 128), 256, 0, stream>>>(
        h_b, qkvT_l, qkv_b + l * QKV_N, nullptr, nullptr, qkv_a, NTOK, QKV_N, D_MODEL);
    attn_kernel<<<dim3(SEQ / 64, 2 * NHEAD), 256, 0, stream>>>(qkv_a, at_b);
    gemm_kernel<2, 64><<<dim3(D_MODEL / 64, NTOK / 128), 256, 0, stream>>>(
        at_b, outT_l, out_b + l * D_MODEL, resid_in, buf_x2, nullptr, NTOK, D_MODEL, D_MODEL);
    ln_kernel<<<NTOK, 256, 0, stream>>>(buf_x2, ln2_w + l * D_MODEL, ln2_b + l * D_MODEL, h_b);
    gemm_kernel<1, 128><<<dim3(D_FF / 128, NTOK / 128), 256, 0, stream>>>(
        h_b, f1T_l, fc1_b + l * D_FF, nullptr, nullptr, mlp_b, NTOK, D_FF, D_MODEL);
    float* x_next = (l < 3) ? buf_x : (float*)d_out;
    gemm_kernel<2, 64><<<dim3(D_MODEL / 64, NTOK / 128), 256, 0, stream>>>(
        mlp_b, f2T_l, fc2_b + l * D_MODEL, buf_x2, x_next, nullptr, NTOK, D_MODEL, D_FF);
  }
  (void)in_sizes; (void)n_in; (void)out_size;
}